// Round 2
// baseline (1539.934 us; speedup 1.0000x reference)
//
#include <hip/hip_runtime.h>
#include <hip/hip_bf16.h>
#include <stdint.h>

// FT-Transformer forward, MI355X gfx950. Round 7:
//  - gemm_frag: block tile 256x128 (4 waves, wave tile 128x64, 8x4 fragment grid).
//    Raises FLOP/LDS-byte 21 -> 29 and flips the kernel from LDS-port-bound (round 6
//    measurement: 144KB/CU/step ~= port peak) to MFMA-issue-bound. LDS 48KB dbuf,
//    ~200 VGPR -> 2 blocks/CU for barrier-drain overlap.
//  - M padded to 16640 (65 x 256) so no M-guards in GEMM; pad rows are dataflow-
//    contained (row-wise dependency only, never read by attn/LN/out_copy).
//  - tokenizer / LN / attention / weight transform unchanged.

typedef __hip_bfloat16 bf16_t;
typedef __attribute__((ext_vector_type(8))) __bf16 bf16x8;
typedef __attribute__((ext_vector_type(4))) float floatx4;

constexpr int M_ROWS = 16512;          // 128 * 129 real rows
constexpr int MP_ROWS = 16640;         // padded to 65 * 256
constexpr float SQRT_EMB_F = 22.627416997969522f;  // scores DIVIDED by emb**-0.5

__device__ __forceinline__ floatx4 mfma16(bf16x8 a, bf16x8 b, floatx4 c) {
  return __builtin_amdgcn_mfma_f32_16x16x32_bf16(a, b, c, 0, 0, 0);
}

__device__ __forceinline__ void gload_lds16(const bf16_t* g, bf16_t* l) {
  __builtin_amdgcn_global_load_lds(
      (const __attribute__((address_space(1))) void*)g,
      (__attribute__((address_space(3))) void*)l, 16, 0, 0);
}

// element offset of the 16B chunk holding (m, k..k+7) in fragment-tiled [M/16][KT][512]
__device__ __forceinline__ size_t frag_chunk(int m, int k, int KT) {
  return ((size_t)(m >> 4) * KT + (k >> 5)) * 512 + (m & 15) * 8 + 128 * ((k >> 3) & 3);
}
// element offset of scalar (m, k)
__device__ __forceinline__ size_t frag_elem(int m, int k, int KT) {
  return frag_chunk(m, k, KT) + (k & 7);
}

// ---------------- weight transform: W [L][K][N] fp32 -> frag-tiled bf16 [L][N/16][KP/32][512]
// PERM=1: output col n maps to source col (n&1) ? 682+(n>>1) : (n>>1)  (ReGLU pairing)
template <int PERM>
__global__ __launch_bounds__(256) void transpose_cvt(const float* __restrict__ W,
    bf16_t* __restrict__ WT, int K, int N, int KP, int NP)
{
  __shared__ float tile[32][33];
  int k0 = blockIdx.x * 32, n0 = blockIdx.y * 32;
  const float* Wl = W + (size_t)blockIdx.z * K * N;
  bf16_t* WTl = WT + (size_t)blockIdx.z * NP * KP;
  const int KT = KP >> 5;
  #pragma unroll
  for (int r = 0; r < 32; r += 8) {
    int k = k0 + threadIdx.y + r, n = n0 + threadIdx.x;
    int srcn = PERM ? ((n & 1) ? 682 + (n >> 1) : (n >> 1)) : n;
    int valid = (k < K) && (PERM ? (n < 1364) : (n < N));
    tile[threadIdx.y + r][threadIdx.x] = valid ? Wl[(size_t)k * N + srcn] : 0.f;
  }
  __syncthreads();
  #pragma unroll
  for (int r = 0; r < 32; r += 8) {
    int n = n0 + threadIdx.y + r, k = k0 + threadIdx.x;
    if (n < NP && k < KP)
      WTl[frag_elem(n, k, KT)] = __float2bfloat16(tile[threadIdx.x][threadIdx.y + r]);
  }
}

// ---------------- feature tokenizer: wave per row; h row-major fp32 + ab frag bf16 ----------------
__global__ __launch_bounds__(256) void tokenizer_kernel(const float* __restrict__ x,
    const float* __restrict__ tok_w, const float* __restrict__ tok_b,
    const float* __restrict__ cat_emb, float* __restrict__ h, bf16_t* __restrict__ ab)
{
  int row = blockIdx.x * 4 + (threadIdx.x >> 6);
  int lane = threadIdx.x & 63, e0 = lane * 8;
  int b = row / 129, t = row - b * 129;
  float v[8];
  if (t == 0) {
    #pragma unroll
    for (int u = 0; u < 8; u++) v[u] = tok_w[e0 + u];
  } else if (t <= 100) {
    float xv = x[(size_t)b * 128 + 28 + (t - 1)];
    const float* wp = tok_w + (size_t)t * 512 + e0;
    const float* bp = tok_b + (size_t)(t - 1) * 512 + e0;
    #pragma unroll
    for (int u = 0; u < 8; u++) v[u] = wp[u] * xv + bp[u];
  } else {
    int j = t - 101;
    int idx = (int)x[(size_t)b * 128 + j] + 100 * j;
    const float* cp = cat_emb + (size_t)idx * 512 + e0;
    const float* bp = tok_b + (size_t)(t - 1) * 512 + e0;
    #pragma unroll
    for (int u = 0; u < 8; u++) v[u] = cp[u] + bp[u];
  }
  float* hr = h + (size_t)row * 512 + e0;
  #pragma unroll
  for (int u = 0; u < 8; u++) hr[u] = v[u];
  bf16x8 o8;
  #pragma unroll
  for (int u = 0; u < 8; u++) o8[u] = (__bf16)__float2bfloat16(v[u]);
  *(bf16x8*)(ab + ((size_t)(row >> 4) * 16 + (lane >> 2)) * 512 + (row & 15) * 8 + 128 * (lane & 3)) = o8;
}

// ---------------- layernorm: one wave per row; out = frag-tiled bf16 (KT=16) ----------------
__global__ __launch_bounds__(256) void ln_kernel(const float* __restrict__ hin,
    bf16_t* __restrict__ out, const float* __restrict__ g, const float* __restrict__ bta)
{
  int row = blockIdx.x * 4 + (threadIdx.x >> 6);
  int lane = threadIdx.x & 63;
  const float* hr = hin + (size_t)row * 512 + lane * 8;
  float4 v0 = *(const float4*)hr;
  float4 v1 = *(const float4*)(hr + 4);
  float s = v0.x + v0.y + v0.z + v0.w + v1.x + v1.y + v1.z + v1.w;
  float q = v0.x * v0.x + v0.y * v0.y + v0.z * v0.z + v0.w * v0.w
          + v1.x * v1.x + v1.y * v1.y + v1.z * v1.z + v1.w * v1.w;
  #pragma unroll
  for (int o = 1; o < 64; o <<= 1) { s += __shfl_xor(s, o); q += __shfl_xor(q, o); }
  float mean = s * (1.f / 512.f);
  float var = q * (1.f / 512.f) - mean * mean;
  float rstd = rsqrtf(var + 1e-5f);
  float4 g0 = *(const float4*)(g + lane * 8);
  float4 g1 = *(const float4*)(g + lane * 8 + 4);
  float4 b0v = *(const float4*)(bta + lane * 8);
  float4 b1v = *(const float4*)(bta + lane * 8 + 4);
  bf16x8 o8;
  o8[0] = (__bf16)__float2bfloat16((v0.x - mean) * rstd * g0.x + b0v.x);
  o8[1] = (__bf16)__float2bfloat16((v0.y - mean) * rstd * g0.y + b0v.y);
  o8[2] = (__bf16)__float2bfloat16((v0.z - mean) * rstd * g0.z + b0v.z);
  o8[3] = (__bf16)__float2bfloat16((v0.w - mean) * rstd * g0.w + b0v.w);
  o8[4] = (__bf16)__float2bfloat16((v1.x - mean) * rstd * g1.x + b1v.x);
  o8[5] = (__bf16)__float2bfloat16((v1.y - mean) * rstd * g1.y + b1v.y);
  o8[6] = (__bf16)__float2bfloat16((v1.z - mean) * rstd * g1.z + b1v.z);
  o8[7] = (__bf16)__float2bfloat16((v1.w - mean) * rstd * g1.w + b1v.w);
  *(bf16x8*)(out + ((size_t)(row >> 4) * 16 + (lane >> 2)) * 512 + (row & 15) * 8 + 128 * (lane & 3)) = o8;
}

// ---------------- frag GEMM: C[M,N] = A * BT^T + bias ----------------
// Block tile 256x128, 4 waves, wave tile 128x64 (8x4 fragment grid).
// A frag-tiled [M/16][K/32][512]; BT frag-tiled [N/16][K/32][512].
// Per K-step (k32): stage next 24KB (16 A-tiles + 8 B-tiles) via global_load_lds,
// ds_read 12 frags, 32 MFMA, one __syncthreads (drains vmcnt). Double-buffered LDS.
// MODE 0: out bf16 frag-tiled (KT_out = N/32).
// MODE 1: out fp32 row-major = resid + acc + bias (N==512).
// MODE 2: ReGLU: paired cols (a=even,b=odd), out bf16 frag-tiled [M/16][(N/2)/32][512].
template <int MODE>
__global__ __launch_bounds__(256, 2) void gemm_frag(const bf16_t* __restrict__ A,
    const bf16_t* __restrict__ BT, const float* __restrict__ bias, int biasN,
    const float* __restrict__ resid, void* __restrict__ outp, int K, int N)
{
  __shared__ bf16_t lsA[2][16][512];   // 32 KB
  __shared__ bf16_t lsB[2][8][512];    // 16 KB

  // XCD-aware remap: blocks with lin%8==x get a contiguous idx chunk
  const int total = gridDim.x * gridDim.y;
  const int lin = blockIdx.y * gridDim.x + blockIdx.x;
  const int xcd = lin & 7, kb2 = lin >> 3;
  const int qch = total >> 3, rch = total & 7;
  const int idx = xcd * qch + (xcd < rch ? xcd : rch) + kb2;
  const int bm = idx / gridDim.x;
  const int bn = idx - bm * gridDim.x;
  const int m0 = bm * 256, n0 = bn * 128;

  const int tid = threadIdx.x;
  const int w = tid >> 6, l = tid & 63, l15 = l & 15, quad = l >> 4;
  const int wm = (w >> 1) * 128, wn = (w & 1) * 64;
  const int KT = K >> 5;

  // staging: wave w owns A-tiles {4w..4w+3} and B-tiles {2w,2w+1}
  const bf16_t* gA[4];
  const bf16_t* gB[2];
  #pragma unroll
  for (int s = 0; s < 4; s++)
    gA[s] = A + ((size_t)((m0 >> 4) + 4 * w + s) * KT) * 512 + l * 8;
  #pragma unroll
  for (int s = 0; s < 2; s++)
    gB[s] = BT + ((size_t)((n0 >> 4) + 2 * w + s) * KT) * 512 + l * 8;

  auto stage = [&](int buf, int t) {
    const size_t go = (size_t)t * 512;
    #pragma unroll
    for (int s = 0; s < 4; s++) gload_lds16(gA[s] + go, &lsA[buf][4 * w + s][0]);
    #pragma unroll
    for (int s = 0; s < 2; s++) gload_lds16(gB[s] + go, &lsB[buf][2 * w + s][0]);
  };

  floatx4 z4 = {0.f, 0.f, 0.f, 0.f};
  floatx4 acc[8][4];
  #pragma unroll
  for (int i = 0; i < 8; i++)
    #pragma unroll
    for (int j = 0; j < 4; j++) acc[i][j] = z4;

  stage(0, 0);
  __syncthreads();   // drains vmcnt(0) -> buf0 ready

  const int ra = (w >> 1) * 8;   // lds A tile base this wave reads
  const int rb = (w & 1) * 4;    // lds B tile base this wave reads
  int cur = 0;
  for (int t = 0; t < KT; ++t) {
    if (t + 1 < KT) stage(cur ^ 1, t + 1);   // async DMA, lands during this step
    bf16x8 af[8], bg[4];
    #pragma unroll
    for (int i = 0; i < 8; i++) af[i] = *(const bf16x8*)&lsA[cur][ra + i][l * 8];
    #pragma unroll
    for (int j = 0; j < 4; j++) bg[j] = *(const bf16x8*)&lsB[cur][rb + j][l * 8];
    #pragma unroll
    for (int i = 0; i < 8; i++)
      #pragma unroll
      for (int j = 0; j < 4; j++)
        acc[i][j] = mfma16(af[i], bg[j], acc[i][j]);
    __syncthreads();   // drains vmcnt (next buf staged) + guards buf reuse
    cur ^= 1;
  }

  #pragma unroll
  for (int j = 0; j < 4; j++) {
    int col = n0 + wn + j * 16 + l15;
    float bv = 0.f;
    if (MODE == 2) {
      if (col < biasN) bv = bias[(col & 1) ? 682 + (col >> 1) : (col >> 1)];
    } else {
      if (col < biasN) bv = bias[col];
    }
    #pragma unroll
    for (int i = 0; i < 8; i++) {
      int row_b = m0 + wm + i * 16 + quad * 4;
      #pragma unroll
      for (int r = 0; r < 4; r++) {
        float v = acc[i][j][r] + bv;
        int m = row_b + r;
        if (MODE == 2) {
          float other = __shfl_xor(v, 1);
          if (!(l15 & 1)) {
            int c2 = col >> 1;
            ((bf16_t*)outp)[frag_elem(m, c2, (N >> 1) >> 5)] =
                __float2bfloat16(v * fmaxf(other, 0.f));
          }
        } else if (MODE == 1) {
          size_t idx2 = (size_t)m * N + col;
          ((float*)outp)[idx2] = v + resid[idx2];
        } else {
          ((bf16_t*)outp)[frag_elem(m, col, N >> 5)] = __float2bfloat16(v);
        }
      }
    }
  }
}

// ---------------- fused attention: one block per (batch, head) ----------------
// qkv frag-tiled over [M, 1536] (KT=48); head hh: q at col hh*192, k +64, v +128.
constexpr int SP = 160;  // S=129 padded to 5*32
__global__ __launch_bounds__(256) void attn_kernel(const bf16_t* __restrict__ qkv,
                                                   bf16_t* __restrict__ attnout)
{
  __shared__ bf16_t vt_lds[64 * SP];   // [d][s_kv]
  __shared__ float sc[32 * SP];        // scores; p (bf16) overlays
  bf16_t* p_lds = (bf16_t*)sc;
  __bf16* vt_raw = (__bf16*)vt_lds;

  const int bh = blockIdx.x, b = bh >> 3, hh = bh & 7;
  const int tid = threadIdx.x;
  const int w = tid >> 6, l = tid & 63, l15 = l & 15, quad = l >> 4;
  const int rbase = b * 129;

  for (int i = tid; i < SP * 64 / 2; i += 256) ((unsigned int*)vt_lds)[i] = 0u;
  __syncthreads();
  for (int c = tid; c < 129 * 8; c += 256) {
    int s = c >> 3, ch = c & 7;
    bf16x8 tv = *(const bf16x8*)(qkv + frag_chunk(rbase + s, hh * 192 + 128 + ch * 8, 48));
    #pragma unroll
    for (int j = 0; j < 8; j++) vt_raw[(size_t)(ch * 8 + j) * SP + s] = tv[j];
  }
  __syncthreads();

  for (int qt = 0; qt < 5; qt++) {
    bf16x8 zq = {};
    bf16x8 aq[2][2];
    #pragma unroll
    for (int mt = 0; mt < 2; mt++) {
      int m = qt * 32 + mt * 16 + l15;
      #pragma unroll
      for (int t = 0; t < 2; t++)
        aq[mt][t] = (m < 129)
            ? *(const bf16x8*)(qkv + frag_chunk(rbase + m, hh * 192 + t * 32 + quad * 8, 48)) : zq;
    }
    for (int nt = w; nt < 10; nt += 4) {
      int krow = nt * 16 + l15;
      floatx4 a0 = {0.f, 0.f, 0.f, 0.f}, a1 = {0.f, 0.f, 0.f, 0.f};
      #pragma unroll
      for (int t = 0; t < 2; t++) {
        bf16x8 kf = (krow < 129)
            ? *(const bf16x8*)(qkv + frag_chunk(rbase + krow, hh * 192 + 64 + t * 32 + quad * 8, 48))
            : zq;
        a0 = mfma16(aq[0][t], kf, a0);
        a1 = mfma16(aq[1][t], kf, a1);
      }
      #pragma unroll
      for (int r = 0; r < 4; r++) {
        sc[(quad * 4 + r) * SP + nt * 16 + l15]      = a0[r] * SQRT_EMB_F;
        sc[(16 + quad * 4 + r) * SP + nt * 16 + l15] = a1[r] * SQRT_EMB_F;
      }
    }
    __syncthreads();

    // double softmax, 8 threads per row
    {
      int row = tid >> 3, sub = tid & 7;
      float vv[20];
      float mx = -1e30f;
      #pragma unroll
      for (int c = 0; c < 20; c++) {
        int j = sub + c * 8;
        vv[c] = (j < 129) ? sc[row * SP + j] : -1e30f;
        mx = fmaxf(mx, vv[c]);
      }
      #pragma unroll
      for (int o = 1; o < 8; o <<= 1) mx = fmaxf(mx, __shfl_xor(mx, o, 8));
      float sum = 0.f;
      #pragma unroll
      for (int c = 0; c < 20; c++) {
        int j = sub + c * 8;
        vv[c] = (j < 129) ? __expf(vv[c] - mx) : 0.f;
        sum += vv[c];
      }
      #pragma unroll
      for (int o = 1; o < 8; o <<= 1) sum += __shfl_xor(sum, o, 8);
      float inv = 1.f / sum;
      float mx2 = 0.f;
      #pragma unroll
      for (int c = 0; c < 20; c++) { vv[c] *= inv; mx2 = fmaxf(mx2, vv[c]); }
      #pragma unroll
      for (int o = 1; o < 8; o <<= 1) mx2 = fmaxf(mx2, __shfl_xor(mx2, o, 8));
      float sum2 = 0.f;
      #pragma unroll
      for (int c = 0; c < 20; c++) {
        int j = sub + c * 8;
        vv[c] = (j < 129) ? __expf(vv[c] - mx2) : 0.f;
        sum2 += vv[c];
      }
      #pragma unroll
      for (int o = 1; o < 8; o <<= 1) sum2 += __shfl_xor(sum2, o, 8);
      float inv2 = 1.f / sum2;
      __syncthreads();
      #pragma unroll
      for (int c = 0; c < 20; c++) {
        int j = sub + c * 8;
        p_lds[row * SP + j] = __float2bfloat16(vv[c] * inv2);  // pads -> 0
      }
    }
    __syncthreads();

    // PV: o[32,64] = p[32,160] @ v[160,64]; store attno in frag layout (KT=16)
    {
      int mt = w >> 1, nt0 = (w & 1) * 2;
      floatx4 oacc[2];
      oacc[0] = floatx4{0.f, 0.f, 0.f, 0.f};
      oacc[1] = floatx4{0.f, 0.f, 0.f, 0.f};
      #pragma unroll
      for (int t = 0; t < 5; t++) {
        bf16x8 pf = *(const bf16x8*)&p_lds[(mt * 16 + l15) * SP + t * 32 + quad * 8];
        #pragma unroll
        for (int n = 0; n < 2; n++) {
          bf16x8 vf = *(const bf16x8*)&vt_lds[((nt0 + n) * 16 + l15) * SP + t * 32 + quad * 8];
          oacc[n] = mfma16(pf, vf, oacc[n]);
        }
      }
      #pragma unroll
      for (int n = 0; n < 2; n++)
        #pragma unroll
        for (int r = 0; r < 4; r++) {
          int sq = qt * 32 + mt * 16 + quad * 4 + r;
          if (sq < 129) {
            int cc = hh * 64 + (nt0 + n) * 16 + l15;
            attnout[frag_elem(rbase + sq, cc, 16)] = __float2bfloat16(oacc[n][r]);
          }
        }
    }
    __syncthreads();
  }
}

// ---------------- output: CLS rows ----------------
__global__ __launch_bounds__(256) void out_copy(const float* __restrict__ h,
                                                float* __restrict__ out)
{
  int b = blockIdx.x, e = threadIdx.x;
  out[(size_t)b * 512 + e]       = h[(size_t)b * 129 * 512 + e];
  out[(size_t)b * 512 + e + 256] = h[(size_t)b * 129 * 512 + e + 256];
}

// ---------------- host launcher ----------------
extern "C" void kernel_launch(void* const* d_in, const int* in_sizes, int n_in,
                              void* d_out, int out_size, void* d_ws, size_t ws_size,
                              hipStream_t stream)
{
  const float* x       = (const float*)d_in[0];
  const float* tok_w   = (const float*)d_in[1];
  const float* tok_b   = (const float*)d_in[2];
  const float* cat_emb = (const float*)d_in[3];
  const float* Wqkv    = (const float*)d_in[4];
  const float* bqkv    = (const float*)d_in[5];
  const float* Wout    = (const float*)d_in[6];
  const float* bout    = (const float*)d_in[7];
  const float* W0      = (const float*)d_in[8];
  const float* b0      = (const float*)d_in[9];
  const float* W1      = (const float*)d_in[10];
  const float* b1      = (const float*)d_in[11];
  const float* ln0_g   = (const float*)d_in[12];
  const float* ln0_b   = (const float*)d_in[13];
  const float* ln1_g   = (const float*)d_in[14];
  const float* ln1_b   = (const float*)d_in[15];

  size_t off = 0;
  char* base = (char*)d_ws;
  auto alloc = [&](size_t n) { char* p = base + off; off += (n + 255) & ~(size_t)255; return p; };
  float*  h     = (float*) alloc((size_t)MP_ROWS * 512 * 4);
  bf16_t* ab    = (bf16_t*)alloc((size_t)MP_ROWS * 512 * 2);   // LN out, frag KT=16
  bf16_t* qkv   = (bf16_t*)alloc((size_t)MP_ROWS * 1536 * 2);  // frag KT=48
  bf16_t* attno = (bf16_t*)alloc((size_t)MP_ROWS * 512 * 2);   // frag KT=16
  bf16_t* regl  = (bf16_t*)alloc((size_t)MP_ROWS * 704 * 2);   // frag KT=22
  bf16_t* WqkvT = (bf16_t*)alloc((size_t)6 * 1536 * 512 * 2);
  bf16_t* WoutT = (bf16_t*)alloc((size_t)6 * 512 * 512 * 2);
  bf16_t* W0T   = (bf16_t*)alloc((size_t)6 * 1408 * 512 * 2);  // pair-interleaved
  bf16_t* W1T   = (bf16_t*)alloc((size_t)6 * 512 * 704 * 2);
  (void)ws_size; (void)in_sizes; (void)n_in; (void)out_size;

  dim3 tb(32, 8, 1);
  transpose_cvt<0><<<dim3(16, 48, 6), tb, 0, stream>>>(Wqkv, WqkvT, 512, 1536, 512, 1536);
  transpose_cvt<0><<<dim3(16, 16, 6), tb, 0, stream>>>(Wout, WoutT, 512, 512, 512, 512);
  transpose_cvt<1><<<dim3(16, 44, 6), tb, 0, stream>>>(W0, W0T, 512, 1364, 512, 1408);
  transpose_cvt<0><<<dim3(22, 16, 6), tb, 0, stream>>>(W1, W1T, 682, 512, 704, 512);

  tokenizer_kernel<<<M_ROWS / 4, 256, 0, stream>>>(x, tok_w, tok_b, cat_emb, h, ab);

  for (int i = 0; i < 6; i++) {
    if (i)
      ln_kernel<<<M_ROWS / 4, 256, 0, stream>>>(h, ab, ln0_g + (size_t)i * 512,
                                                ln0_b + (size_t)i * 512);
    gemm_frag<0><<<dim3(12, 65), 256, 0, stream>>>(
        ab, WqkvT + (size_t)i * 1536 * 512, bqkv + (size_t)i * 1536, 1536, nullptr, qkv, 512, 1536);
    attn_kernel<<<1024, 256, 0, stream>>>(qkv, attno);
    gemm_frag<1><<<dim3(4, 65), 256, 0, stream>>>(
        attno, WoutT + (size_t)i * 512 * 512, bout + (size_t)i * 512, 512, h, h, 512, 512);
    ln_kernel<<<M_ROWS / 4, 256, 0, stream>>>(h, ab, ln1_g + (size_t)i * 512,
                                              ln1_b + (size_t)i * 512);
    gemm_frag<2><<<dim3(11, 65), 256, 0, stream>>>(
        ab, W0T + (size_t)i * 1408 * 512, b0 + (size_t)i * 1364, 1364, nullptr, regl, 512, 1408);
    gemm_frag<1><<<dim3(4, 65), 256, 0, stream>>>(
        regl, W1T + (size_t)i * 512 * 704, b1 + (size_t)i * 512, 512, h, h, 704, 512);
  }

  out_copy<<<128, 256, 0, stream>>>(h, (float*)d_out);
}

// Round 3
// 1311.678 us; speedup vs baseline: 1.1740x; 1.1740x over previous
//
#include <hip/hip_runtime.h>
#include <hip/hip_bf16.h>
#include <stdint.h>

// FT-Transformer forward, MI355X gfx950. Round 8:
//  - revert gemm_frag geometry to round-6's 128x128 / 4-wave / 64x64-per-wave (best
//    measured), but replace the drain-to-zero __syncthreads loop with a 3-buffer
//    counted-vmcnt pipeline (T4): issue stage(t+2) after the barrier, compute buf[t],
//    then s_waitcnt vmcnt(4) (stage(t+1) done, stage(t+2) stays in flight) + raw
//    s_barrier. DMA never drains in the main loop.
//  - everything else (tokenizer, LN, attention, epilogues, weight transform) unchanged.

typedef __hip_bfloat16 bf16_t;
typedef __attribute__((ext_vector_type(8))) __bf16 bf16x8;
typedef __attribute__((ext_vector_type(4))) float floatx4;

constexpr int M_ROWS = 16512;          // 128 * 129
constexpr float SQRT_EMB_F = 22.627416997969522f;  // scores DIVIDED by emb**-0.5

__device__ __forceinline__ floatx4 mfma16(bf16x8 a, bf16x8 b, floatx4 c) {
  return __builtin_amdgcn_mfma_f32_16x16x32_bf16(a, b, c, 0, 0, 0);
}

__device__ __forceinline__ void gload_lds16(const bf16_t* g, bf16_t* l) {
  __builtin_amdgcn_global_load_lds(
      (const __attribute__((address_space(1))) void*)g,
      (__attribute__((address_space(3))) void*)l, 16, 0, 0);
}

// element offset of the 16B chunk holding (m, k..k+7) in fragment-tiled [M/16][KT][512]
__device__ __forceinline__ size_t frag_chunk(int m, int k, int KT) {
  return ((size_t)(m >> 4) * KT + (k >> 5)) * 512 + (m & 15) * 8 + 128 * ((k >> 3) & 3);
}
// element offset of scalar (m, k)
__device__ __forceinline__ size_t frag_elem(int m, int k, int KT) {
  return frag_chunk(m, k, KT) + (k & 7);
}

// ---------------- weight transform: W [L][K][N] fp32 -> frag-tiled bf16 [L][N/16][KP/32][512]
// PERM=1: output col n maps to source col (n&1) ? 682+(n>>1) : (n>>1)  (ReGLU pairing)
template <int PERM>
__global__ __launch_bounds__(256) void transpose_cvt(const float* __restrict__ W,
    bf16_t* __restrict__ WT, int K, int N, int KP, int NP)
{
  __shared__ float tile[32][33];
  int k0 = blockIdx.x * 32, n0 = blockIdx.y * 32;
  const float* Wl = W + (size_t)blockIdx.z * K * N;
  bf16_t* WTl = WT + (size_t)blockIdx.z * NP * KP;
  const int KT = KP >> 5;
  #pragma unroll
  for (int r = 0; r < 32; r += 8) {
    int k = k0 + threadIdx.y + r, n = n0 + threadIdx.x;
    int srcn = PERM ? ((n & 1) ? 682 + (n >> 1) : (n >> 1)) : n;
    int valid = (k < K) && (PERM ? (n < 1364) : (n < N));
    tile[threadIdx.y + r][threadIdx.x] = valid ? Wl[(size_t)k * N + srcn] : 0.f;
  }
  __syncthreads();
  #pragma unroll
  for (int r = 0; r < 32; r += 8) {
    int n = n0 + threadIdx.y + r, k = k0 + threadIdx.x;
    if (n < NP && k < KP)
      WTl[frag_elem(n, k, KT)] = __float2bfloat16(tile[threadIdx.x][threadIdx.y + r]);
  }
}

// ---------------- feature tokenizer: wave per row; h row-major fp32 + ab frag bf16 ----------------
__global__ __launch_bounds__(256) void tokenizer_kernel(const float* __restrict__ x,
    const float* __restrict__ tok_w, const float* __restrict__ tok_b,
    const float* __restrict__ cat_emb, float* __restrict__ h, bf16_t* __restrict__ ab)
{
  int row = blockIdx.x * 4 + (threadIdx.x >> 6);
  int lane = threadIdx.x & 63, e0 = lane * 8;
  int b = row / 129, t = row - b * 129;
  float v[8];
  if (t == 0) {
    #pragma unroll
    for (int u = 0; u < 8; u++) v[u] = tok_w[e0 + u];
  } else if (t <= 100) {
    float xv = x[(size_t)b * 128 + 28 + (t - 1)];
    const float* wp = tok_w + (size_t)t * 512 + e0;
    const float* bp = tok_b + (size_t)(t - 1) * 512 + e0;
    #pragma unroll
    for (int u = 0; u < 8; u++) v[u] = wp[u] * xv + bp[u];
  } else {
    int j = t - 101;
    int idx = (int)x[(size_t)b * 128 + j] + 100 * j;
    const float* cp = cat_emb + (size_t)idx * 512 + e0;
    const float* bp = tok_b + (size_t)(t - 1) * 512 + e0;
    #pragma unroll
    for (int u = 0; u < 8; u++) v[u] = cp[u] + bp[u];
  }
  float* hr = h + (size_t)row * 512 + e0;
  #pragma unroll
  for (int u = 0; u < 8; u++) hr[u] = v[u];
  bf16x8 o8;
  #pragma unroll
  for (int u = 0; u < 8; u++) o8[u] = (__bf16)__float2bfloat16(v[u]);
  *(bf16x8*)(ab + ((size_t)(row >> 4) * 16 + (lane >> 2)) * 512 + (row & 15) * 8 + 128 * (lane & 3)) = o8;
}

// ---------------- layernorm: one wave per row; out = frag-tiled bf16 (KT=16) ----------------
__global__ __launch_bounds__(256) void ln_kernel(const float* __restrict__ hin,
    bf16_t* __restrict__ out, const float* __restrict__ g, const float* __restrict__ bta)
{
  int row = blockIdx.x * 4 + (threadIdx.x >> 6);
  int lane = threadIdx.x & 63;
  const float* hr = hin + (size_t)row * 512 + lane * 8;
  float4 v0 = *(const float4*)hr;
  float4 v1 = *(const float4*)(hr + 4);
  float s = v0.x + v0.y + v0.z + v0.w + v1.x + v1.y + v1.z + v1.w;
  float q = v0.x * v0.x + v0.y * v0.y + v0.z * v0.z + v0.w * v0.w
          + v1.x * v1.x + v1.y * v1.y + v1.z * v1.z + v1.w * v1.w;
  #pragma unroll
  for (int o = 1; o < 64; o <<= 1) { s += __shfl_xor(s, o); q += __shfl_xor(q, o); }
  float mean = s * (1.f / 512.f);
  float var = q * (1.f / 512.f) - mean * mean;
  float rstd = rsqrtf(var + 1e-5f);
  float4 g0 = *(const float4*)(g + lane * 8);
  float4 g1 = *(const float4*)(g + lane * 8 + 4);
  float4 b0v = *(const float4*)(bta + lane * 8);
  float4 b1v = *(const float4*)(bta + lane * 8 + 4);
  bf16x8 o8;
  o8[0] = (__bf16)__float2bfloat16((v0.x - mean) * rstd * g0.x + b0v.x);
  o8[1] = (__bf16)__float2bfloat16((v0.y - mean) * rstd * g0.y + b0v.y);
  o8[2] = (__bf16)__float2bfloat16((v0.z - mean) * rstd * g0.z + b0v.z);
  o8[3] = (__bf16)__float2bfloat16((v0.w - mean) * rstd * g0.w + b0v.w);
  o8[4] = (__bf16)__float2bfloat16((v1.x - mean) * rstd * g1.x + b1v.x);
  o8[5] = (__bf16)__float2bfloat16((v1.y - mean) * rstd * g1.y + b1v.y);
  o8[6] = (__bf16)__float2bfloat16((v1.z - mean) * rstd * g1.z + b1v.z);
  o8[7] = (__bf16)__float2bfloat16((v1.w - mean) * rstd * g1.w + b1v.w);
  *(bf16x8*)(out + ((size_t)(row >> 4) * 16 + (lane >> 2)) * 512 + (row & 15) * 8 + 128 * (lane & 3)) = o8;
}

// ---------------- frag GEMM: C[M,N] = A * BT^T + bias ----------------
// 128x128 block tile, 4 waves (64x64 each). A frag-tiled [M/16][K/32][512];
// BT frag-tiled [N/16][K/32][512]. 3-buffer LDS pipeline with counted vmcnt:
// per step issue stage(t+2) after the barrier, compute buf[t], then
// s_waitcnt vmcnt(4) (stage(t+1) landed; stage(t+2) still in flight) + raw s_barrier.
// MODE 0: out bf16 frag-tiled (KT_out = N/32).
// MODE 1: out fp32 row-major = resid + acc + bias (N==512).
// MODE 2: ReGLU: paired cols (a=even,b=odd), out bf16 frag-tiled [M/16][(N/2)/32][512].
template <int MODE>
__global__ __launch_bounds__(256, 3) void gemm_frag(const bf16_t* __restrict__ A,
    const bf16_t* __restrict__ BT, const float* __restrict__ bias, int biasN,
    const float* __restrict__ resid, void* __restrict__ outp, int K, int N)
{
  __shared__ bf16_t lsA[3][8][512];   // 24 KB
  __shared__ bf16_t lsB[3][8][512];   // 24 KB

  // XCD-aware remap: blocks with lin%8==x get a contiguous idx chunk
  const int total = gridDim.x * gridDim.y;
  const int lin = blockIdx.y * gridDim.x + blockIdx.x;
  const int xcd = lin & 7, kb2 = lin >> 3;
  const int qch = total >> 3, rch = total & 7;
  const int idx = xcd * qch + (xcd < rch ? xcd : rch) + kb2;
  const int bm = idx / gridDim.x;
  const int bn = idx - bm * gridDim.x;
  const int m0 = bm * 128, n0 = bn * 128;

  const int tid = threadIdx.x;
  const int w = tid >> 6, l = tid & 63, l15 = l & 15, quad = l >> 4;
  const int wm = (w >> 1) * 64, wn = (w & 1) * 64;
  const int KT = K >> 5;

  // staging: wave w owns A-tiles {2w,2w+1} and B-tiles {2w,2w+1} of this block tile
  const bf16_t* gA0 = A  + ((size_t)((m0 >> 4) + 2 * w) * KT) * 512 + l * 8;
  const bf16_t* gA1 = gA0 + (size_t)KT * 512;
  const bf16_t* gB0 = BT + ((size_t)((n0 >> 4) + 2 * w) * KT) * 512 + l * 8;
  const bf16_t* gB1 = gB0 + (size_t)KT * 512;
  const int sa = w * 2;          // lds tile index this wave stages
  const int ra = (w >> 1) * 4;   // lds A tile base this wave reads
  const int rb = (w & 1) * 4;    // lds B tile base this wave reads

  auto stage = [&](int buf, int t) {
    const size_t go = (size_t)t * 512;
    gload_lds16(gA0 + go, &lsA[buf][sa][0]);
    gload_lds16(gA1 + go, &lsA[buf][sa + 1][0]);
    gload_lds16(gB0 + go, &lsB[buf][sa][0]);
    gload_lds16(gB1 + go, &lsB[buf][sa + 1][0]);
  };

  floatx4 z4 = {0.f, 0.f, 0.f, 0.f};
  floatx4 acc[4][4];
  #pragma unroll
  for (int i = 0; i < 4; i++)
    #pragma unroll
    for (int j = 0; j < 4; j++) acc[i][j] = z4;

  // prologue: prefetch steps 0 and 1; wait only for step 0 (4 newest stay in flight)
  stage(0, 0);
  stage(1, 1);
  asm volatile("s_waitcnt vmcnt(4)" ::: "memory");
  __builtin_amdgcn_s_barrier();

  int cur = 0;
  for (int t = 0; t < KT; ++t) {
    // stage t+2 into the buffer freed at step t-1 (safe: barrier above)
    if (t + 2 < KT) {
      int s2 = cur + 2 >= 3 ? cur - 1 : cur + 2;
      stage(s2, t + 2);
    }
    bf16x8 af[4], bg[4];
    #pragma unroll
    for (int i = 0; i < 4; i++) {
      af[i] = *(const bf16x8*)&lsA[cur][ra + i][l * 8];
      bg[i] = *(const bf16x8*)&lsB[cur][rb + i][l * 8];
    }
    #pragma unroll
    for (int i = 0; i < 4; i++)
      #pragma unroll
      for (int j = 0; j < 4; j++)
        acc[i][j] = mfma16(af[i], bg[j], acc[i][j]);
    if (t + 1 < KT) {
      // wait for stage(t+1) only; stage(t+2) (newest 4 loads) stays in flight
      if (t + 2 < KT) asm volatile("s_waitcnt vmcnt(4)" ::: "memory");
      else            asm volatile("s_waitcnt vmcnt(0)" ::: "memory");
      __builtin_amdgcn_s_barrier();
    }
    cur = cur + 1 >= 3 ? 0 : cur + 1;
  }

  #pragma unroll
  for (int j = 0; j < 4; j++) {
    int col = n0 + wn + j * 16 + l15;
    float bv = 0.f;
    if (MODE == 2) {
      if (col < biasN) bv = bias[(col & 1) ? 682 + (col >> 1) : (col >> 1)];
    } else {
      if (col < biasN) bv = bias[col];
    }
    #pragma unroll
    for (int i = 0; i < 4; i++) {
      int row_b = m0 + wm + i * 16 + quad * 4;
      #pragma unroll
      for (int r = 0; r < 4; r++) {
        float v = acc[i][j][r] + bv;
        int m = row_b + r;
        if (MODE == 2) {
          float other = __shfl_xor(v, 1);
          if (!(l15 & 1)) {
            int c2 = col >> 1;
            ((bf16_t*)outp)[frag_elem(m, c2, (N >> 1) >> 5)] =
                __float2bfloat16(v * fmaxf(other, 0.f));
          }
        } else if (MODE == 1) {
          size_t idx2 = (size_t)m * N + col;
          ((float*)outp)[idx2] = v + resid[idx2];
        } else {
          ((bf16_t*)outp)[frag_elem(m, col, N >> 5)] = __float2bfloat16(v);
        }
      }
    }
  }
}

// ---------------- fused attention: one block per (batch, head) ----------------
// qkv frag-tiled over [M, 1536] (KT=48); head hh: q at col hh*192, k +64, v +128.
constexpr int SP = 160;  // S=129 padded to 5*32
__global__ __launch_bounds__(256) void attn_kernel(const bf16_t* __restrict__ qkv,
                                                   bf16_t* __restrict__ attnout)
{
  __shared__ bf16_t vt_lds[64 * SP];   // [d][s_kv]
  __shared__ float sc[32 * SP];        // scores; p (bf16) overlays
  bf16_t* p_lds = (bf16_t*)sc;
  __bf16* vt_raw = (__bf16*)vt_lds;

  const int bh = blockIdx.x, b = bh >> 3, hh = bh & 7;
  const int tid = threadIdx.x;
  const int w = tid >> 6, l = tid & 63, l15 = l & 15, quad = l >> 4;
  const int rbase = b * 129;

  for (int i = tid; i < SP * 64 / 2; i += 256) ((unsigned int*)vt_lds)[i] = 0u;
  __syncthreads();
  for (int c = tid; c < 129 * 8; c += 256) {
    int s = c >> 3, ch = c & 7;
    bf16x8 tv = *(const bf16x8*)(qkv + frag_chunk(rbase + s, hh * 192 + 128 + ch * 8, 48));
    #pragma unroll
    for (int j = 0; j < 8; j++) vt_raw[(size_t)(ch * 8 + j) * SP + s] = tv[j];
  }
  __syncthreads();

  for (int qt = 0; qt < 5; qt++) {
    bf16x8 zq = {};
    bf16x8 aq[2][2];
    #pragma unroll
    for (int mt = 0; mt < 2; mt++) {
      int m = qt * 32 + mt * 16 + l15;
      #pragma unroll
      for (int t = 0; t < 2; t++)
        aq[mt][t] = (m < 129)
            ? *(const bf16x8*)(qkv + frag_chunk(rbase + m, hh * 192 + t * 32 + quad * 8, 48)) : zq;
    }
    for (int nt = w; nt < 10; nt += 4) {
      int krow = nt * 16 + l15;
      floatx4 a0 = {0.f, 0.f, 0.f, 0.f}, a1 = {0.f, 0.f, 0.f, 0.f};
      #pragma unroll
      for (int t = 0; t < 2; t++) {
        bf16x8 kf = (krow < 129)
            ? *(const bf16x8*)(qkv + frag_chunk(rbase + krow, hh * 192 + 64 + t * 32 + quad * 8, 48))
            : zq;
        a0 = mfma16(aq[0][t], kf, a0);
        a1 = mfma16(aq[1][t], kf, a1);
      }
      #pragma unroll
      for (int r = 0; r < 4; r++) {
        sc[(quad * 4 + r) * SP + nt * 16 + l15]      = a0[r] * SQRT_EMB_F;
        sc[(16 + quad * 4 + r) * SP + nt * 16 + l15] = a1[r] * SQRT_EMB_F;
      }
    }
    __syncthreads();

    // double softmax, 8 threads per row
    {
      int row = tid >> 3, sub = tid & 7;
      float vv[20];
      float mx = -1e30f;
      #pragma unroll
      for (int c = 0; c < 20; c++) {
        int j = sub + c * 8;
        vv[c] = (j < 129) ? sc[row * SP + j] : -1e30f;
        mx = fmaxf(mx, vv[c]);
      }
      #pragma unroll
      for (int o = 1; o < 8; o <<= 1) mx = fmaxf(mx, __shfl_xor(mx, o, 8));
      float sum = 0.f;
      #pragma unroll
      for (int c = 0; c < 20; c++) {
        int j = sub + c * 8;
        vv[c] = (j < 129) ? __expf(vv[c] - mx) : 0.f;
        sum += vv[c];
      }
      #pragma unroll
      for (int o = 1; o < 8; o <<= 1) sum += __shfl_xor(sum, o, 8);
      float inv = 1.f / sum;
      float mx2 = 0.f;
      #pragma unroll
      for (int c = 0; c < 20; c++) { vv[c] *= inv; mx2 = fmaxf(mx2, vv[c]); }
      #pragma unroll
      for (int o = 1; o < 8; o <<= 1) mx2 = fmaxf(mx2, __shfl_xor(mx2, o, 8));
      float sum2 = 0.f;
      #pragma unroll
      for (int c = 0; c < 20; c++) {
        int j = sub + c * 8;
        vv[c] = (j < 129) ? __expf(vv[c] - mx2) : 0.f;
        sum2 += vv[c];
      }
      #pragma unroll
      for (int o = 1; o < 8; o <<= 1) sum2 += __shfl_xor(sum2, o, 8);
      float inv2 = 1.f / sum2;
      __syncthreads();
      #pragma unroll
      for (int c = 0; c < 20; c++) {
        int j = sub + c * 8;
        p_lds[row * SP + j] = __float2bfloat16(vv[c] * inv2);  // pads -> 0
      }
    }
    __syncthreads();

    // PV: o[32,64] = p[32,160] @ v[160,64]; store attno in frag layout (KT=16)
    {
      int mt = w >> 1, nt0 = (w & 1) * 2;
      floatx4 oacc[2];
      oacc[0] = floatx4{0.f, 0.f, 0.f, 0.f};
      oacc[1] = floatx4{0.f, 0.f, 0.f, 0.f};
      #pragma unroll
      for (int t = 0; t < 5; t++) {
        bf16x8 pf = *(const bf16x8*)&p_lds[(mt * 16 + l15) * SP + t * 32 + quad * 8];
        #pragma unroll
        for (int n = 0; n < 2; n++) {
          bf16x8 vf = *(const bf16x8*)&vt_lds[((nt0 + n) * 16 + l15) * SP + t * 32 + quad * 8];
          oacc[n] = mfma16(pf, vf, oacc[n]);
        }
      }
      #pragma unroll
      for (int n = 0; n < 2; n++)
        #pragma unroll
        for (int r = 0; r < 4; r++) {
          int sq = qt * 32 + mt * 16 + quad * 4 + r;
          if (sq < 129) {
            int cc = hh * 64 + (nt0 + n) * 16 + l15;
            attnout[frag_elem(rbase + sq, cc, 16)] = __float2bfloat16(oacc[n][r]);
          }
        }
    }
    __syncthreads();
  }
}

// ---------------- output: CLS rows ----------------
__global__ __launch_bounds__(256) void out_copy(const float* __restrict__ h,
                                                float* __restrict__ out)
{
  int b = blockIdx.x, e = threadIdx.x;
  out[(size_t)b * 512 + e]       = h[(size_t)b * 129 * 512 + e];
  out[(size_t)b * 512 + e + 256] = h[(size_t)b * 129 * 512 + e + 256];
}

// ---------------- host launcher ----------------
extern "C" void kernel_launch(void* const* d_in, const int* in_sizes, int n_in,
                              void* d_out, int out_size, void* d_ws, size_t ws_size,
                              hipStream_t stream)
{
  const float* x       = (const float*)d_in[0];
  const float* tok_w   = (const float*)d_in[1];
  const float* tok_b   = (const float*)d_in[2];
  const float* cat_emb = (const float*)d_in[3];
  const float* Wqkv    = (const float*)d_in[4];
  const float* bqkv    = (const float*)d_in[5];
  const float* Wout    = (const float*)d_in[6];
  const float* bout    = (const float*)d_in[7];
  const float* W0      = (const float*)d_in[8];
  const float* b0      = (const float*)d_in[9];
  const float* W1      = (const float*)d_in[10];
  const float* b1      = (const float*)d_in[11];
  const float* ln0_g   = (const float*)d_in[12];
  const float* ln0_b   = (const float*)d_in[13];
  const float* ln1_g   = (const float*)d_in[14];
  const float* ln1_b   = (const float*)d_in[15];

  size_t off = 0;
  char* base = (char*)d_ws;
  auto alloc = [&](size_t n) { char* p = base + off; off += (n + 255) & ~(size_t)255; return p; };
  float*  h     = (float*) alloc((size_t)M_ROWS * 512 * 4);
  bf16_t* ab    = (bf16_t*)alloc((size_t)M_ROWS * 512 * 2);   // LN out, frag KT=16
  bf16_t* qkv   = (bf16_t*)alloc((size_t)M_ROWS * 1536 * 2);  // frag KT=48
  bf16_t* attno = (bf16_t*)alloc((size_t)M_ROWS * 512 * 2);   // frag KT=16
  bf16_t* regl  = (bf16_t*)alloc((size_t)M_ROWS * 704 * 2);   // frag KT=22
  bf16_t* WqkvT = (bf16_t*)alloc((size_t)6 * 1536 * 512 * 2);
  bf16_t* WoutT = (bf16_t*)alloc((size_t)6 * 512 * 512 * 2);
  bf16_t* W0T   = (bf16_t*)alloc((size_t)6 * 1408 * 512 * 2);  // pair-interleaved
  bf16_t* W1T   = (bf16_t*)alloc((size_t)6 * 512 * 704 * 2);
  (void)ws_size; (void)in_sizes; (void)n_in; (void)out_size;

  dim3 tb(32, 8, 1);
  transpose_cvt<0><<<dim3(16, 48, 6), tb, 0, stream>>>(Wqkv, WqkvT, 512, 1536, 512, 1536);
  transpose_cvt<0><<<dim3(16, 16, 6), tb, 0, stream>>>(Wout, WoutT, 512, 512, 512, 512);
  transpose_cvt<1><<<dim3(16, 44, 6), tb, 0, stream>>>(W0, W0T, 512, 1364, 512, 1408);
  transpose_cvt<0><<<dim3(22, 16, 6), tb, 0, stream>>>(W1, W1T, 682, 512, 704, 512);

  tokenizer_kernel<<<M_ROWS / 4, 256, 0, stream>>>(x, tok_w, tok_b, cat_emb, h, ab);

  for (int i = 0; i < 6; i++) {
    if (i)
      ln_kernel<<<M_ROWS / 4, 256, 0, stream>>>(h, ab, ln0_g + (size_t)i * 512,
                                                ln0_b + (size_t)i * 512);
    gemm_frag<0><<<dim3(12, 129), 256, 0, stream>>>(
        ab, WqkvT + (size_t)i * 1536 * 512, bqkv + (size_t)i * 1536, 1536, nullptr, qkv, 512, 1536);
    attn_kernel<<<1024, 256, 0, stream>>>(qkv, attno);
    gemm_frag<1><<<dim3(4, 129), 256, 0, stream>>>(
        attno, WoutT + (size_t)i * 512 * 512, bout + (size_t)i * 512, 512, h, h, 512, 512);
    ln_kernel<<<M_ROWS / 4, 256, 0, stream>>>(h, ab, ln1_g + (size_t)i * 512,
                                              ln1_b + (size_t)i * 512);
    gemm_frag<2><<<dim3(11, 129), 256, 0, stream>>>(
        ab, W0T + (size_t)i * 1408 * 512, b0 + (size_t)i * 1364, 1364, nullptr, regl, 512, 1408);
    gemm_frag<1><<<dim3(4, 129), 256, 0, stream>>>(
        regl, W1T + (size_t)i * 512 * 704, b1 + (size_t)i * 512, 512, h, h, 704, 512);
  }

  out_copy<<<128, 256, 0, stream>>>(h, (float*)d_out);
}

// Round 4
// 1269.674 us; speedup vs baseline: 1.2129x; 1.0331x over previous
//
#include <hip/hip_runtime.h>
#include <hip/hip_bf16.h>
#include <stdint.h>

// FT-Transformer forward, MI355X gfx950. Round 9:
//  - gemm_frag: round-6 structure (128x128, 4 waves, 2-buf LDS + __syncthreads per
//    K-step — best measured) with two changes:
//    (a) __launch_bounds__(256,4): combined VGPR+acc ~120 fits 4 waves/SIMD; round-6's
//        bound of 3 was the occupancy cap (28% measured).
//    (b) C^T accumulation: acc = mfma(bg, af, acc). Thread then holds 4 CONSECUTIVE
//        output columns -> vectorized epilogue: MODE0 16x8B stores (was 64x2B),
//        MODE1 16x float4 (was 64 scalar), MODE2 ReGLU pair is thread-local
//        (no shuffles, 8x4B stores).
//  - tokenizer / LN / attention / weight transform unchanged.

typedef __hip_bfloat16 bf16_t;
typedef __attribute__((ext_vector_type(8))) __bf16 bf16x8;
typedef __attribute__((ext_vector_type(4))) __bf16 bf16x4;
typedef __attribute__((ext_vector_type(2))) __bf16 bf16x2;
typedef __attribute__((ext_vector_type(4))) float floatx4;

constexpr int M_ROWS = 16512;          // 128 * 129
constexpr float SQRT_EMB_F = 22.627416997969522f;  // scores DIVIDED by emb**-0.5

__device__ __forceinline__ floatx4 mfma16(bf16x8 a, bf16x8 b, floatx4 c) {
  return __builtin_amdgcn_mfma_f32_16x16x32_bf16(a, b, c, 0, 0, 0);
}

__device__ __forceinline__ void gload_lds16(const bf16_t* g, bf16_t* l) {
  __builtin_amdgcn_global_load_lds(
      (const __attribute__((address_space(1))) void*)g,
      (__attribute__((address_space(3))) void*)l, 16, 0, 0);
}

// element offset of the 16B chunk holding (m, k..k+7) in fragment-tiled [M/16][KT][512]
__device__ __forceinline__ size_t frag_chunk(int m, int k, int KT) {
  return ((size_t)(m >> 4) * KT + (k >> 5)) * 512 + (m & 15) * 8 + 128 * ((k >> 3) & 3);
}
// element offset of scalar (m, k)
__device__ __forceinline__ size_t frag_elem(int m, int k, int KT) {
  return frag_chunk(m, k, KT) + (k & 7);
}

// ---------------- weight transform: W [L][K][N] fp32 -> frag-tiled bf16 [L][N/16][KP/32][512]
// PERM=1: output col n maps to source col (n&1) ? 682+(n>>1) : (n>>1)  (ReGLU pairing)
template <int PERM>
__global__ __launch_bounds__(256) void transpose_cvt(const float* __restrict__ W,
    bf16_t* __restrict__ WT, int K, int N, int KP, int NP)
{
  __shared__ float tile[32][33];
  int k0 = blockIdx.x * 32, n0 = blockIdx.y * 32;
  const float* Wl = W + (size_t)blockIdx.z * K * N;
  bf16_t* WTl = WT + (size_t)blockIdx.z * NP * KP;
  const int KT = KP >> 5;
  #pragma unroll
  for (int r = 0; r < 32; r += 8) {
    int k = k0 + threadIdx.y + r, n = n0 + threadIdx.x;
    int srcn = PERM ? ((n & 1) ? 682 + (n >> 1) : (n >> 1)) : n;
    int valid = (k < K) && (PERM ? (n < 1364) : (n < N));
    tile[threadIdx.y + r][threadIdx.x] = valid ? Wl[(size_t)k * N + srcn] : 0.f;
  }
  __syncthreads();
  #pragma unroll
  for (int r = 0; r < 32; r += 8) {
    int n = n0 + threadIdx.y + r, k = k0 + threadIdx.x;
    if (n < NP && k < KP)
      WTl[frag_elem(n, k, KT)] = __float2bfloat16(tile[threadIdx.x][threadIdx.y + r]);
  }
}

// ---------------- feature tokenizer: wave per row; h row-major fp32 + ab frag bf16 ----------------
__global__ __launch_bounds__(256) void tokenizer_kernel(const float* __restrict__ x,
    const float* __restrict__ tok_w, const float* __restrict__ tok_b,
    const float* __restrict__ cat_emb, float* __restrict__ h, bf16_t* __restrict__ ab)
{
  int row = blockIdx.x * 4 + (threadIdx.x >> 6);
  int lane = threadIdx.x & 63, e0 = lane * 8;
  int b = row / 129, t = row - b * 129;
  float v[8];
  if (t == 0) {
    #pragma unroll
    for (int u = 0; u < 8; u++) v[u] = tok_w[e0 + u];
  } else if (t <= 100) {
    float xv = x[(size_t)b * 128 + 28 + (t - 1)];
    const float* wp = tok_w + (size_t)t * 512 + e0;
    const float* bp = tok_b + (size_t)(t - 1) * 512 + e0;
    #pragma unroll
    for (int u = 0; u < 8; u++) v[u] = wp[u] * xv + bp[u];
  } else {
    int j = t - 101;
    int idx = (int)x[(size_t)b * 128 + j] + 100 * j;
    const float* cp = cat_emb + (size_t)idx * 512 + e0;
    const float* bp = tok_b + (size_t)(t - 1) * 512 + e0;
    #pragma unroll
    for (int u = 0; u < 8; u++) v[u] = cp[u] + bp[u];
  }
  float* hr = h + (size_t)row * 512 + e0;
  #pragma unroll
  for (int u = 0; u < 8; u++) hr[u] = v[u];
  bf16x8 o8;
  #pragma unroll
  for (int u = 0; u < 8; u++) o8[u] = (__bf16)__float2bfloat16(v[u]);
  *(bf16x8*)(ab + ((size_t)(row >> 4) * 16 + (lane >> 2)) * 512 + (row & 15) * 8 + 128 * (lane & 3)) = o8;
}

// ---------------- layernorm: one wave per row; out = frag-tiled bf16 (KT=16) ----------------
__global__ __launch_bounds__(256) void ln_kernel(const float* __restrict__ hin,
    bf16_t* __restrict__ out, const float* __restrict__ g, const float* __restrict__ bta)
{
  int row = blockIdx.x * 4 + (threadIdx.x >> 6);
  int lane = threadIdx.x & 63;
  const float* hr = hin + (size_t)row * 512 + lane * 8;
  float4 v0 = *(const float4*)hr;
  float4 v1 = *(const float4*)(hr + 4);
  float s = v0.x + v0.y + v0.z + v0.w + v1.x + v1.y + v1.z + v1.w;
  float q = v0.x * v0.x + v0.y * v0.y + v0.z * v0.z + v0.w * v0.w
          + v1.x * v1.x + v1.y * v1.y + v1.z * v1.z + v1.w * v1.w;
  #pragma unroll
  for (int o = 1; o < 64; o <<= 1) { s += __shfl_xor(s, o); q += __shfl_xor(q, o); }
  float mean = s * (1.f / 512.f);
  float var = q * (1.f / 512.f) - mean * mean;
  float rstd = rsqrtf(var + 1e-5f);
  float4 g0 = *(const float4*)(g + lane * 8);
  float4 g1 = *(const float4*)(g + lane * 8 + 4);
  float4 b0v = *(const float4*)(bta + lane * 8);
  float4 b1v = *(const float4*)(bta + lane * 8 + 4);
  bf16x8 o8;
  o8[0] = (__bf16)__float2bfloat16((v0.x - mean) * rstd * g0.x + b0v.x);
  o8[1] = (__bf16)__float2bfloat16((v0.y - mean) * rstd * g0.y + b0v.y);
  o8[2] = (__bf16)__float2bfloat16((v0.z - mean) * rstd * g0.z + b0v.z);
  o8[3] = (__bf16)__float2bfloat16((v0.w - mean) * rstd * g0.w + b0v.w);
  o8[4] = (__bf16)__float2bfloat16((v1.x - mean) * rstd * g1.x + b1v.x);
  o8[5] = (__bf16)__float2bfloat16((v1.y - mean) * rstd * g1.y + b1v.y);
  o8[6] = (__bf16)__float2bfloat16((v1.z - mean) * rstd * g1.z + b1v.z);
  o8[7] = (__bf16)__float2bfloat16((v1.w - mean) * rstd * g1.w + b1v.w);
  *(bf16x8*)(out + ((size_t)(row >> 4) * 16 + (lane >> 2)) * 512 + (row & 15) * 8 + 128 * (lane & 3)) = o8;
}

// ---------------- frag GEMM: C[M,N] = A * BT^T + bias ----------------
// 128x128 block tile, 4 waves (64x64 each). A frag-tiled [M/16][K/32][512];
// BT frag-tiled [N/16][K/32][512]. 2-buf LDS + __syncthreads per K-step.
// C^T accumulation: acc = mfma(bg, af, acc) -> lane l15 = output ROW (m),
// quad*4+r = output COL (n); thread holds 4 consecutive cols -> vector stores.
// MODE 0: out bf16 frag-tiled (KT_out = N/32).
// MODE 1: out fp32 row-major = resid + acc + bias (N==512==biasN).
// MODE 2: ReGLU: paired cols (a=even,b=odd) thread-local, out bf16 frag-tiled
//         [M/16][(N/2)/32][512].
template <int MODE>
__global__ __launch_bounds__(256, 4) void gemm_frag(const bf16_t* __restrict__ A,
    const bf16_t* __restrict__ BT, const float* __restrict__ bias, int biasN,
    const float* __restrict__ resid, void* __restrict__ outp, int K, int N)
{
  __shared__ bf16_t lsA[2][8][512];   // 16 KB
  __shared__ bf16_t lsB[2][8][512];   // 16 KB

  // XCD-aware remap: blocks with lin%8==x get a contiguous idx chunk
  const int total = gridDim.x * gridDim.y;
  const int lin = blockIdx.y * gridDim.x + blockIdx.x;
  const int xcd = lin & 7, kb2 = lin >> 3;
  const int qch = total >> 3, rch = total & 7;
  const int idx = xcd * qch + (xcd < rch ? xcd : rch) + kb2;
  const int bm = idx / gridDim.x;
  const int bn = idx - bm * gridDim.x;
  const int m0 = bm * 128, n0 = bn * 128;

  const int tid = threadIdx.x;
  const int w = tid >> 6, l = tid & 63, l15 = l & 15, quad = l >> 4;
  const int wm = (w >> 1) * 64, wn = (w & 1) * 64;
  const int KT = K >> 5;

  // staging: wave w owns A-tiles {2w,2w+1} and B-tiles {2w,2w+1} of this block tile
  const bf16_t* gA0 = A  + ((size_t)((m0 >> 4) + 2 * w) * KT) * 512 + l * 8;
  const bf16_t* gA1 = gA0 + (size_t)KT * 512;
  const bf16_t* gB0 = BT + ((size_t)((n0 >> 4) + 2 * w) * KT) * 512 + l * 8;
  const bf16_t* gB1 = gB0 + (size_t)KT * 512;
  const int sa = w * 2;          // lds tile index this wave stages
  const int ra = (w >> 1) * 4;   // lds A tile base this wave reads
  const int rb = (w & 1) * 4;    // lds B tile base this wave reads

  auto stage = [&](int buf, int t) {
    const size_t go = (size_t)t * 512;
    gload_lds16(gA0 + go, &lsA[buf][sa][0]);
    gload_lds16(gA1 + go, &lsA[buf][sa + 1][0]);
    gload_lds16(gB0 + go, &lsB[buf][sa][0]);
    gload_lds16(gB1 + go, &lsB[buf][sa + 1][0]);
  };

  floatx4 z4 = {0.f, 0.f, 0.f, 0.f};
  floatx4 acc[4][4];
  #pragma unroll
  for (int i = 0; i < 4; i++)
    #pragma unroll
    for (int j = 0; j < 4; j++) acc[i][j] = z4;

  stage(0, 0);
  __syncthreads();   // compiler drains vmcnt(0) before barrier -> buf0 ready

  int cur = 0;
  for (int t = 0; t < KT; ++t) {
    if (t + 1 < KT) stage(cur ^ 1, t + 1);   // async DMA, in flight across this step
    bf16x8 af[4], bg[4];
    #pragma unroll
    for (int i = 0; i < 4; i++) {
      af[i] = *(const bf16x8*)&lsA[cur][ra + i][l * 8];
      bg[i] = *(const bf16x8*)&lsB[cur][rb + i][l * 8];
    }
    #pragma unroll
    for (int i = 0; i < 4; i++)
      #pragma unroll
      for (int j = 0; j < 4; j++)
        acc[i][j] = mfma16(bg[j], af[i], acc[i][j]);   // C^T
    __syncthreads();   // drains vmcnt (next buf staged) + guards buf reuse
    cur ^= 1;
  }

  // epilogue: thread owns rows m = m0+wm+i*16+l15, cols nb..nb+3 (consecutive)
  #pragma unroll
  for (int i = 0; i < 4; i++) {
    int m = m0 + wm + i * 16 + l15;
    #pragma unroll
    for (int j = 0; j < 4; j++) {
      int nb = n0 + wn + j * 16 + quad * 4;
      if (MODE == 2) {
        int c2b = nb >> 1;
        bf16x2 o2;
        #pragma unroll
        for (int u = 0; u < 2; u++) {
          int c2 = c2b + u;
          bool vld = (2 * c2 < biasN);
          float av = acc[i][j][2 * u]     + (vld ? bias[c2] : 0.f);
          float bv = acc[i][j][2 * u + 1] + (vld ? bias[682 + c2] : 0.f);
          o2[u] = (__bf16)__float2bfloat16(av * fmaxf(bv, 0.f));
        }
        *(bf16x2*)&((bf16_t*)outp)[frag_elem(m, c2b, (N >> 1) >> 5)] = o2;
      } else if (MODE == 1) {
        size_t idx2 = (size_t)m * N + nb;
        float4 rv = *(const float4*)(resid + idx2);
        float4 ov;
        ov.x = acc[i][j][0] + bias[nb + 0] + rv.x;
        ov.y = acc[i][j][1] + bias[nb + 1] + rv.y;
        ov.z = acc[i][j][2] + bias[nb + 2] + rv.z;
        ov.w = acc[i][j][3] + bias[nb + 3] + rv.w;
        *(float4*)((float*)outp + idx2) = ov;
      } else {
        bf16x4 o4;
        #pragma unroll
        for (int r = 0; r < 4; r++) {
          float bv = (nb + r < biasN) ? bias[nb + r] : 0.f;
          o4[r] = (__bf16)__float2bfloat16(acc[i][j][r] + bv);
        }
        *(bf16x4*)&((bf16_t*)outp)[frag_elem(m, nb, N >> 5)] = o4;
      }
    }
  }
}

// ---------------- fused attention: one block per (batch, head) ----------------
// qkv frag-tiled over [M, 1536] (KT=48); head hh: q at col hh*192, k +64, v +128.
constexpr int SP = 160;  // S=129 padded to 5*32
__global__ __launch_bounds__(256) void attn_kernel(const bf16_t* __restrict__ qkv,
                                                   bf16_t* __restrict__ attnout)
{
  __shared__ bf16_t vt_lds[64 * SP];   // [d][s_kv]
  __shared__ float sc[32 * SP];        // scores; p (bf16) overlays
  bf16_t* p_lds = (bf16_t*)sc;
  __bf16* vt_raw = (__bf16*)vt_lds;

  const int bh = blockIdx.x, b = bh >> 3, hh = bh & 7;
  const int tid = threadIdx.x;
  const int w = tid >> 6, l = tid & 63, l15 = l & 15, quad = l >> 4;
  const int rbase = b * 129;

  for (int i = tid; i < SP * 64 / 2; i += 256) ((unsigned int*)vt_lds)[i] = 0u;
  __syncthreads();
  for (int c = tid; c < 129 * 8; c += 256) {
    int s = c >> 3, ch = c & 7;
    bf16x8 tv = *(const bf16x8*)(qkv + frag_chunk(rbase + s, hh * 192 + 128 + ch * 8, 48));
    #pragma unroll
    for (int j = 0; j < 8; j++) vt_raw[(size_t)(ch * 8 + j) * SP + s] = tv[j];
  }
  __syncthreads();

  for (int qt = 0; qt < 5; qt++) {
    bf16x8 zq = {};
    bf16x8 aq[2][2];
    #pragma unroll
    for (int mt = 0; mt < 2; mt++) {
      int m = qt * 32 + mt * 16 + l15;
      #pragma unroll
      for (int t = 0; t < 2; t++)
        aq[mt][t] = (m < 129)
            ? *(const bf16x8*)(qkv + frag_chunk(rbase + m, hh * 192 + t * 32 + quad * 8, 48)) : zq;
    }
    for (int nt = w; nt < 10; nt += 4) {
      int krow = nt * 16 + l15;
      floatx4 a0 = {0.f, 0.f, 0.f, 0.f}, a1 = {0.f, 0.f, 0.f, 0.f};
      #pragma unroll
      for (int t = 0; t < 2; t++) {
        bf16x8 kf = (krow < 129)
            ? *(const bf16x8*)(qkv + frag_chunk(rbase + krow, hh * 192 + 64 + t * 32 + quad * 8, 48))
            : zq;
        a0 = mfma16(aq[0][t], kf, a0);
        a1 = mfma16(aq[1][t], kf, a1);
      }
      #pragma unroll
      for (int r = 0; r < 4; r++) {
        sc[(quad * 4 + r) * SP + nt * 16 + l15]      = a0[r] * SQRT_EMB_F;
        sc[(16 + quad * 4 + r) * SP + nt * 16 + l15] = a1[r] * SQRT_EMB_F;
      }
    }
    __syncthreads();

    // double softmax, 8 threads per row
    {
      int row = tid >> 3, sub = tid & 7;
      float vv[20];
      float mx = -1e30f;
      #pragma unroll
      for (int c = 0; c < 20; c++) {
        int j = sub + c * 8;
        vv[c] = (j < 129) ? sc[row * SP + j] : -1e30f;
        mx = fmaxf(mx, vv[c]);
      }
      #pragma unroll
      for (int o = 1; o < 8; o <<= 1) mx = fmaxf(mx, __shfl_xor(mx, o, 8));
      float sum = 0.f;
      #pragma unroll
      for (int c = 0; c < 20; c++) {
        int j = sub + c * 8;
        vv[c] = (j < 129) ? __expf(vv[c] - mx) : 0.f;
        sum += vv[c];
      }
      #pragma unroll
      for (int o = 1; o < 8; o <<= 1) sum += __shfl_xor(sum, o, 8);
      float inv = 1.f / sum;
      float mx2 = 0.f;
      #pragma unroll
      for (int c = 0; c < 20; c++) { vv[c] *= inv; mx2 = fmaxf(mx2, vv[c]); }
      #pragma unroll
      for (int o = 1; o < 8; o <<= 1) mx2 = fmaxf(mx2, __shfl_xor(mx2, o, 8));
      float sum2 = 0.f;
      #pragma unroll
      for (int c = 0; c < 20; c++) {
        int j = sub + c * 8;
        vv[c] = (j < 129) ? __expf(vv[c] - mx2) : 0.f;
        sum2 += vv[c];
      }
      #pragma unroll
      for (int o = 1; o < 8; o <<= 1) sum2 += __shfl_xor(sum2, o, 8);
      float inv2 = 1.f / sum2;
      __syncthreads();
      #pragma unroll
      for (int c = 0; c < 20; c++) {
        int j = sub + c * 8;
        p_lds[row * SP + j] = __float2bfloat16(vv[c] * inv2);  // pads -> 0
      }
    }
    __syncthreads();

    // PV: o[32,64] = p[32,160] @ v[160,64]; store attno in frag layout (KT=16)
    {
      int mt = w >> 1, nt0 = (w & 1) * 2;
      floatx4 oacc[2];
      oacc[0] = floatx4{0.f, 0.f, 0.f, 0.f};
      oacc[1] = floatx4{0.f, 0.f, 0.f, 0.f};
      #pragma unroll
      for (int t = 0; t < 5; t++) {
        bf16x8 pf = *(const bf16x8*)&p_lds[(mt * 16 + l15) * SP + t * 32 + quad * 8];
        #pragma unroll
        for (int n = 0; n < 2; n++) {
          bf16x8 vf = *(const bf16x8*)&vt_lds[((nt0 + n) * 16 + l15) * SP + t * 32 + quad * 8];
          oacc[n] = mfma16(pf, vf, oacc[n]);
        }
      }
      #pragma unroll
      for (int n = 0; n < 2; n++)
        #pragma unroll
        for (int r = 0; r < 4; r++) {
          int sq = qt * 32 + mt * 16 + quad * 4 + r;
          if (sq < 129) {
            int cc = hh * 64 + (nt0 + n) * 16 + l15;
            attnout[frag_elem(rbase + sq, cc, 16)] = __float2bfloat16(oacc[n][r]);
          }
        }
    }
    __syncthreads();
  }
}

// ---------------- output: CLS rows ----------------
__global__ __launch_bounds__(256) void out_copy(const float* __restrict__ h,
                                                float* __restrict__ out)
{
  int b = blockIdx.x, e = threadIdx.x;
  out[(size_t)b * 512 + e]       = h[(size_t)b * 129 * 512 + e];
  out[(size_t)b * 512 + e + 256] = h[(size_t)b * 129 * 512 + e + 256];
}

// ---------------- host launcher ----------------
extern "C" void kernel_launch(void* const* d_in, const int* in_sizes, int n_in,
                              void* d_out, int out_size, void* d_ws, size_t ws_size,
                              hipStream_t stream)
{
  const float* x       = (const float*)d_in[0];
  const float* tok_w   = (const float*)d_in[1];
  const float* tok_b   = (const float*)d_in[2];
  const float* cat_emb = (const float*)d_in[3];
  const float* Wqkv    = (const float*)d_in[4];
  const float* bqkv    = (const float*)d_in[5];
  const float* Wout    = (const float*)d_in[6];
  const float* bout    = (const float*)d_in[7];
  const float* W0      = (const float*)d_in[8];
  const float* b0      = (const float*)d_in[9];
  const float* W1      = (const float*)d_in[10];
  const float* b1      = (const float*)d_in[11];
  const float* ln0_g   = (const float*)d_in[12];
  const float* ln0_b   = (const float*)d_in[13];
  const float* ln1_g   = (const float*)d_in[14];
  const float* ln1_b   = (const float*)d_in[15];

  size_t off = 0;
  char* base = (char*)d_ws;
  auto alloc = [&](size_t n) { char* p = base + off; off += (n + 255) & ~(size_t)255; return p; };
  float*  h     = (float*) alloc((size_t)M_ROWS * 512 * 4);
  bf16_t* ab    = (bf16_t*)alloc((size_t)M_ROWS * 512 * 2);   // LN out, frag KT=16
  bf16_t* qkv   = (bf16_t*)alloc((size_t)M_ROWS * 1536 * 2);  // frag KT=48
  bf16_t* attno = (bf16_t*)alloc((size_t)M_ROWS * 512 * 2);   // frag KT=16
  bf16_t* regl  = (bf16_t*)alloc((size_t)M_ROWS * 704 * 2);   // frag KT=22
  bf16_t* WqkvT = (bf16_t*)alloc((size_t)6 * 1536 * 512 * 2);
  bf16_t* WoutT = (bf16_t*)alloc((size_t)6 * 512 * 512 * 2);
  bf16_t* W0T   = (bf16_t*)alloc((size_t)6 * 1408 * 512 * 2);  // pair-interleaved
  bf16_t* W1T   = (bf16_t*)alloc((size_t)6 * 512 * 704 * 2);
  (void)ws_size; (void)in_sizes; (void)n_in; (void)out_size;

  dim3 tb(32, 8, 1);
  transpose_cvt<0><<<dim3(16, 48, 6), tb, 0, stream>>>(Wqkv, WqkvT, 512, 1536, 512, 1536);
  transpose_cvt<0><<<dim3(16, 16, 6), tb, 0, stream>>>(Wout, WoutT, 512, 512, 512, 512);
  transpose_cvt<1><<<dim3(16, 44, 6), tb, 0, stream>>>(W0, W0T, 512, 1364, 512, 1408);
  transpose_cvt<0><<<dim3(22, 16, 6), tb, 0, stream>>>(W1, W1T, 682, 512, 704, 512);

  tokenizer_kernel<<<M_ROWS / 4, 256, 0, stream>>>(x, tok_w, tok_b, cat_emb, h, ab);

  for (int i = 0; i < 6; i++) {
    if (i)
      ln_kernel<<<M_ROWS / 4, 256, 0, stream>>>(h, ab, ln0_g + (size_t)i * 512,
                                                ln0_b + (size_t)i * 512);
    gemm_frag<0><<<dim3(12, 129), 256, 0, stream>>>(
        ab, WqkvT + (size_t)i * 1536 * 512, bqkv + (size_t)i * 1536, 1536, nullptr, qkv, 512, 1536);
    attn_kernel<<<1024, 256, 0, stream>>>(qkv, attno);
    gemm_frag<1><<<dim3(4, 129), 256, 0, stream>>>(
        attno, WoutT + (size_t)i * 512 * 512, bout + (size_t)i * 512, 512, h, h, 512, 512);
    ln_kernel<<<M_ROWS / 4, 256, 0, stream>>>(h, ab, ln1_g + (size_t)i * 512,
                                              ln1_b + (size_t)i * 512);
    gemm_frag<2><<<dim3(11, 129), 256, 0, stream>>>(
        ab, W0T + (size_t)i * 1408 * 512, b0 + (size_t)i * 1364, 1364, nullptr, regl, 512, 1408);
    gemm_frag<1><<<dim3(4, 129), 256, 0, stream>>>(
        regl, W1T + (size_t)i * 512 * 704, b1 + (size_t)i * 512, 512, h, h, 704, 512);
  }

  out_copy<<<128, 256, 0, stream>>>(h, (float*)d_out);
}